// Round 4
// baseline (2038.523 us; speedup 1.0000x reference)
//
#include <hip/hip_runtime.h>
#include <math.h>

#define BB 128
#define T2 2050
#define TT 2049
#define HH 64
#define GG 448   // 7*H
#define KK 100
#define NE 103   // K+3

#define LOG2E 1.44269504088896340736f
#define LN2   0.69314718055994530942f

// gfx9 waitcnt imm: vmcnt[3:0]|[15:14], expcnt[6:4], lgkmcnt[11:8]
// 0xC07F = lgkmcnt(0), vmcnt=63 (no wait), expcnt=7 (no wait)
#define WAIT_LGKM0 0xC07Fu

__device__ __forceinline__ float frcp(float x) { return __builtin_amdgcn_rcpf(x); }
__device__ __forceinline__ float sigmoid_fast(float x) {
    return frcp(1.f + exp2f(-x * LOG2E));
}
__device__ __forceinline__ float tanh_fast(float x) {
    float e = exp2f(x * (2.f * LOG2E));
    return 1.f - 2.f * frcp(1.f + e);
}
__device__ __forceinline__ float softplus_fast(float x) {
    float t = exp2f(-fabsf(x) * LOG2E);
    return fmaxf(x, 0.f) + LN2 * log2f(1.f + t);
}
__device__ __forceinline__ float rl(float v, int k) {
    return __int_as_float(__builtin_amdgcn_readlane(__float_as_int(v), k));
}

// pre_emb[e][g] = sum_k in_emb[e][k] * Wx[k][g] + bias[g]   (103 x 448)
__global__ void pre_emb_kernel(const float* __restrict__ in_emb,
                               const float* __restrict__ Wx,
                               const float* __restrict__ bias,
                               float* __restrict__ pre_emb) {
    int e = blockIdx.x;
    int g = threadIdx.x;
    float acc = bias[g];
#pragma unroll
    for (int k = 0; k < HH; ++k)
        acc = fmaf(in_emb[e * HH + k], Wx[k * GG + g], acc);
    pre_emb[e * GG + g] = acc;
}

// One block per batch row; 4 waves (256 threads), 1 wave/SIMD.
// Key change vs R3: the per-step barrier is a RAW s_barrier preceded by
// s_waitcnt lgkmcnt(0) ONLY — global loads (pre_emb prefetch) and stores
// (logits) stay in flight across it instead of being drained every step
// (__syncthreads would force vmcnt(0)). ev/dt are staged in LDS at prologue
// so the steady-state loop's only global ops are the latency-tolerant
// prefetch + fire-and-forget stores.
// Work split: all threads gate g=tid; waves 0-2 also gate g=256+tid (wave 2's
// second dot is the delta gate: it pre-applies softplus AND the exp2 decay
// before the barrier, removing exp2+dt from the replicated state update);
// wave 3 also computes logits of h_{t-1} (2 dots) and stores them directly.
// State h/c/cb replicated per wave; h broadcast via v_readlane (no LDS).
// Dot chains use 4-way split accumulators (16-deep fma chains).
__launch_bounds__(256, 1)
__global__ void scan_kernel(const int* __restrict__ event,
                            const float* __restrict__ dtime,
                            const float* __restrict__ pre_emb,
                            const float* __restrict__ Wh,
                            const float* __restrict__ out_emb,
                            float* __restrict__ out) {
    const int b    = blockIdx.x;
    const int tid  = threadIdx.x;
    const int w    = tid >> 6;
    const int lane = tid & 63;
    const bool isw3 = (w == 3);

    __shared__ float gbuf[2][GG];
    __shared__ int   ev_s[T2];
    __shared__ float dt_s[T2];

    const int*   ev_row  = event + b * T2;
    const float* dt_row  = dtime + b * T2;
    float*       out_row = out + (size_t)b * TT * KK;

    // ---- prologue: stage ev/dt rows into LDS (one-time), load weights ----
    for (int i = tid; i < T2; i += 256) {
        ev_s[i] = ev_row[i];
        dt_s[i] = dt_row[i];
    }

    float w1[HH], w2[HH], w3r[HH];
#pragma unroll
    for (int k = 0; k < HH; ++k) w1[k] = Wh[k * GG + tid];
    if (!isw3) {
#pragma unroll
        for (int k = 0; k < HH; ++k) w2[k] = Wh[k * GG + 256 + tid];
    } else {
#pragma unroll
        for (int k = 0; k < HH; ++k) w2[k] = out_emb[lane * HH + k];
#pragma unroll
        for (int k = 0; k < HH; ++k)
            w3r[k] = (lane < 36) ? out_emb[(64 + lane) * HH + k] : 0.f;
    }

    __syncthreads();   // full barrier once: LDS stage visible to all

    int   evn = ev_s[0];
    float pe1 = pre_emb[evn * GG + tid];
    float pe2 = isw3 ? 0.f : pre_emb[evn * GG + 256 + tid];
    evn = ev_s[1];                    // event index for step 1's prefetch
    float dtc = dt_s[1];              // dt for step 0 (decay threads)
    float h = 0.f, c = 0.f, cb = 0.f;

    for (int t = 0; t < TT; ++t) {
        const int buf = t & 1;
        // next-step prefetch: issued now, waited only at use next iteration
        float pe1n = pre_emb[evn * GG + tid];
        float pe2n = isw3 ? 0.f : pre_emb[evn * GG + 256 + tid];
        const int tn  = (t + 2 < TT) ? (t + 2) : (TT - 1);
        int   evn2 = ev_s[tn];                 // ev for step t+2
        float dtn  = dt_s[(t + 2 < T2) ? (t + 2) : (T2 - 1)];  // dt for step t+1

        // ---- dots (4-way split accumulator chains, shared readlanes) ----
        float a1a = 0.f, a1b = 0.f, a1c = 0.f, a1d = 0.f;
        float a2a = 0.f, a2b = 0.f, a2c = 0.f, a2d = 0.f;
        float a3a = 0.f, a3b = 0.f, a3c = 0.f, a3d = 0.f;
#pragma unroll
        for (int k4 = 0; k4 < HH / 4; ++k4) {
            const int k = 4 * k4;
            const float s0 = rl(h, k), s1 = rl(h, k + 1);
            const float s2 = rl(h, k + 2), s3 = rl(h, k + 3);
            a1a = fmaf(s0, w1[k], a1a);
            a1b = fmaf(s1, w1[k + 1], a1b);
            a1c = fmaf(s2, w1[k + 2], a1c);
            a1d = fmaf(s3, w1[k + 3], a1d);
            a2a = fmaf(s0, w2[k], a2a);
            a2b = fmaf(s1, w2[k + 1], a2b);
            a2c = fmaf(s2, w2[k + 2], a2c);
            a2d = fmaf(s3, w2[k + 3], a2d);
            if (isw3) {
                a3a = fmaf(s0, w3r[k], a3a);
                a3b = fmaf(s1, w3r[k + 1], a3b);
                a3c = fmaf(s2, w3r[k + 2], a3c);
                a3d = fmaf(s3, w3r[k + 3], a3d);
            }
        }
        const float a1 = ((a1a + a1b) + (a1c + a1d)) + pe1;

        // gate nonlinearities (pre-barrier)
        float v1 = (w == 2) ? tanh_fast(a1) : sigmoid_fast(a1);
        gbuf[buf][tid] = v1;
        if (!isw3) {
            const float a2 = ((a2a + a2b) + (a2c + a2d)) + pe2;
            float v2;
            if (w == 2) {
                // delta gate -> precompute the full decay factor here so the
                // post-barrier state update needs no exp2 and no dt
                const float sp = softplus_fast(a2);
                v2 = exp2f(-sp * dtc * LOG2E);
            } else {
                v2 = sigmoid_fast(a2);
            }
            gbuf[buf][256 + tid] = v2;
        } else if (t > 0) {
            // logits of h_{t-1}: direct global stores, never drained
            const float a2 = (a2a + a2b) + (a2c + a2d);
            out_row[(size_t)(t - 1) * KK + lane] = softplus_fast(a2);
            if (lane < 36) {
                const float a3 = (a3a + a3b) + (a3c + a3d);
                out_row[(size_t)(t - 1) * KK + 64 + lane] = softplus_fast(a3);
            }
        }

        // ---- raw barrier: LDS-ordered only, vmem stays in flight ----
        __builtin_amdgcn_s_waitcnt(WAIT_LGKM0);
        __builtin_amdgcn_s_barrier();

        // ---- replicated state update (all waves) ----
        const float gi  = gbuf[buf][lane];
        const float gf  = gbuf[buf][64 + lane];
        const float gz  = gbuf[buf][128 + lane];
        const float go  = gbuf[buf][192 + lane];
        const float gib = gbuf[buf][256 + lane];
        const float gfb = gbuf[buf][320 + lane];
        const float dec = gbuf[buf][384 + lane];   // exp(-delta*dt), precomputed
        const float ci  = fmaf(gf, c, gi * gz);
        const float cbi = fmaf(gfb, cb, gib * gz);
        const float cn  = fmaf(ci - cbi, dec, cbi);
        h  = go * tanh_fast(cn);
        c  = cn;
        cb = cbi;
        pe1 = pe1n; pe2 = pe2n; evn = evn2; dtc = dtn;
    }

    // ---- tail: logits of h_{TT-1} (h replicated in wave 3's registers) ----
    if (isw3) {
        float a2a = 0.f, a2b = 0.f, a2c = 0.f, a2d = 0.f;
        float a3a = 0.f, a3b = 0.f, a3c = 0.f, a3d = 0.f;
#pragma unroll
        for (int k4 = 0; k4 < HH / 4; ++k4) {
            const int k = 4 * k4;
            const float s0 = rl(h, k), s1 = rl(h, k + 1);
            const float s2 = rl(h, k + 2), s3 = rl(h, k + 3);
            a2a = fmaf(s0, w2[k], a2a);
            a2b = fmaf(s1, w2[k + 1], a2b);
            a2c = fmaf(s2, w2[k + 2], a2c);
            a2d = fmaf(s3, w2[k + 3], a2d);
            a3a = fmaf(s0, w3r[k], a3a);
            a3b = fmaf(s1, w3r[k + 1], a3b);
            a3c = fmaf(s2, w3r[k + 2], a3c);
            a3d = fmaf(s3, w3r[k + 3], a3d);
        }
        out_row[(size_t)(TT - 1) * KK + lane] =
            softplus_fast((a2a + a2b) + (a2c + a2d));
        if (lane < 36)
            out_row[(size_t)(TT - 1) * KK + 64 + lane] =
                softplus_fast((a3a + a3b) + (a3c + a3d));
    }
}

extern "C" void kernel_launch(void* const* d_in, const int* in_sizes, int n_in,
                              void* d_out, int out_size, void* d_ws, size_t ws_size,
                              hipStream_t stream) {
    const int*   event  = (const int*)d_in[0];
    const float* dtime  = (const float*)d_in[1];
    const float* in_emb = (const float*)d_in[2];
    const float* Wx     = (const float*)d_in[3];
    const float* Wh     = (const float*)d_in[4];
    const float* bias   = (const float*)d_in[5];
    const float* oe     = (const float*)d_in[6];
    float*       out    = (float*)d_out;

    float* pre_emb = (float*)d_ws;  // 103*448*4 = 184,576 bytes

    pre_emb_kernel<<<NE, GG, 0, stream>>>(in_emb, Wx, bias, pre_emb);
    scan_kernel<<<BB, 256, 0, stream>>>(event, dtime, pre_emb, Wh, oe, out);
}